// Round 2
// baseline (403.503 us; speedup 1.0000x reference)
//
#include <hip/hip_runtime.h>
#include <hip/hip_fp16.h>

// GCN 3->32->32->1, N=100K, E=6.4M (+self loops).
// R9: split g into two 3.2MB L2-resident halves -> FETCH 267->35MB/pass but
// dur went UP (118us combined): the pass is instruction/latency-bound, not
// miss-BW-bound (VALU 46%, HBM 7.5%). Per-2B-gather overhead (shfl chain +
// addr calc + scalar load) dominated.
// R10: invert lane layout. 4 lanes/node, each lane owns a whole 16-feature
// half-row per edge: own csr[e] load (NO shfl in hot loop), 2x dwordx4
// gather (32B), 16 fp32 reg accumulators, 2-edge unroll (4 loads in
// flight/lane). Epilogue: 4-lane butterfly + lane-0 fp16 pack (pass A) /
// per-lane 8-output unrolled W2/W3 matmul (pass B). ~3x fewer instruction
// issues per gathered byte. Also 256B-align workspace carves (g/y4 were
// 8 mod 16 -> misaligned dwordx4 rows).
// Carried: fp16 g half-tables (L2-resident), fused k_sort, zero global atomics.

#define BLK 256
#define SB 1280          // chunks; SB*CHUNK == E exactly
#define CHUNK 5000
#define BKT 128          // nodes per bucket
#define NBKT 782         // ceil(100000/128)
#define MAXNB 1024       // scanB width >= NBKT
#define BUFSZ 15360      // k_sort bucket buffer (mean 8192, ~79 sigma)

// ---- pass 1: per-chunk histogram over dst buckets (LDS, int4 loads)
__global__ void k_hist(const int* __restrict__ dst, int* __restrict__ hist, int E) {
    __shared__ int lh[NBKT];
    for (int b = threadIdx.x; b < NBKT; b += blockDim.x) lh[b] = 0;
    __syncthreads();
    int beg = blockIdx.x * CHUNK;
    int end = min(E, beg + CHUNK);
    int nq = (end - beg) >> 2;                    // full int4 quads
    const int4* d4 = (const int4*)(dst + beg);
    for (int i = threadIdx.x; i < nq; i += blockDim.x) {
        int4 d = d4[i];
        atomicAdd(&lh[d.x >> 7], 1);
        atomicAdd(&lh[d.y >> 7], 1);
        atomicAdd(&lh[d.z >> 7], 1);
        atomicAdd(&lh[d.w >> 7], 1);
    }
    for (int e = beg + (nq << 2) + threadIdx.x; e < end; e += blockDim.x)
        atomicAdd(&lh[dst[e] >> 7], 1);
    __syncthreads();
    for (int b = threadIdx.x; b < NBKT; b += blockDim.x)
        hist[(size_t)blockIdx.x * NBKT + b] = lh[b];
}

// ---- scan A: per bucket, exclusive-scan its SB chunk-counts (shfl, 5 items/thr)
__global__ void k_scanA(int* __restrict__ hist, int* __restrict__ btot, int NB) {
    int b = blockIdx.x, t = threadIdx.x;          // 256 threads * 5 items = 1280
    int base = t * 5;
    int v0 = hist[(size_t)(base + 0) * NB + b];
    int v1 = hist[(size_t)(base + 1) * NB + b];
    int v2 = hist[(size_t)(base + 2) * NB + b];
    int v3 = hist[(size_t)(base + 3) * NB + b];
    int v4 = hist[(size_t)(base + 4) * NB + b];
    int s = v0 + v1 + v2 + v3 + v4;
    int lane = t & 63, w = t >> 6;
    int x = s;
#pragma unroll
    for (int off = 1; off < 64; off <<= 1) {
        int u = __shfl_up(x, off, 64);
        if (lane >= off) x += u;
    }
    __shared__ int wsum[4];
    if (lane == 63) wsum[w] = x;
    __syncthreads();
    int woff = 0;
    for (int k = 0; k < 4; k++) woff += (k < w) ? wsum[k] : 0;
    int run = woff + x - s;                       // exclusive prefix for item 0
    hist[(size_t)(base + 0) * NB + b] = run;  run += v0;
    hist[(size_t)(base + 1) * NB + b] = run;  run += v1;
    hist[(size_t)(base + 2) * NB + b] = run;  run += v2;
    hist[(size_t)(base + 3) * NB + b] = run;  run += v3;
    hist[(size_t)(base + 4) * NB + b] = run;  run += v4;
    if (t == 255) btot[b] = run;
}

// ---- scan B: exclusive-scan bucket totals -> bucket base offsets
__global__ void k_scanB(const int* __restrict__ btot, int* __restrict__ bbase,
                        int NB, int E) {
    __shared__ int sh[MAXNB];
    int t = threadIdx.x;
    int v = (t < NB) ? btot[t] : 0;
    sh[t] = v;
    __syncthreads();
    for (int off = 1; off < MAXNB; off <<= 1) {
        int u = (t >= off) ? sh[t - off] : 0;
        __syncthreads();
        sh[t] += u;
        __syncthreads();
    }
    if (t < NB) bbase[t] = sh[t] - v;
    if (t == 0) bbase[NB] = E;
}

// ---- pass 2: LDS chunk-sort by bucket, full-lane sorted-order streaming
__global__ void k_bsort(const int* __restrict__ src, const int* __restrict__ dst,
                        const int* __restrict__ hist, const int* __restrict__ bbase,
                        unsigned int* __restrict__ packed, int E) {
    __shared__ unsigned int bufB[CHUNK];          // 20 KB
    __shared__ unsigned short binarr2[CHUNK];     // 10 KB (bucket of sorted pos)
    __shared__ int cnt[NBKT];
    __shared__ int off[NBKT];
    __shared__ int cur[NBKT];
    __shared__ int gbase[NBKT];
    __shared__ int wsum[4];
    int t = threadIdx.x;
    int beg = blockIdx.x * CHUNK;
    int end = min(E, beg + CHUNK);
    int len = end - beg;
    for (int b = t; b < NBKT; b += blockDim.x) {
        cnt[b] = 0;
        gbase[b] = bbase[b] + hist[(size_t)blockIdx.x * NBKT + b];
    }
    __syncthreads();
    // phase a: count (int4 loads)
    {
        int nq = len >> 2;
        const int4* d4 = (const int4*)(dst + beg);
        for (int i = t; i < nq; i += blockDim.x) {
            int4 d = d4[i];
            atomicAdd(&cnt[d.x >> 7], 1);
            atomicAdd(&cnt[d.y >> 7], 1);
            atomicAdd(&cnt[d.z >> 7], 1);
            atomicAdd(&cnt[d.w >> 7], 1);
        }
        for (int i = (nq << 2) + t; i < len; i += blockDim.x)
            atomicAdd(&cnt[dst[beg + i] >> 7], 1);
    }
    __syncthreads();
    // phase b: exclusive scan of 782 counts (4 items/thread, shfl)
    {
        int base = t * 4;
        int v0 = (base + 0 < NBKT) ? cnt[base + 0] : 0;
        int v1 = (base + 1 < NBKT) ? cnt[base + 1] : 0;
        int v2 = (base + 2 < NBKT) ? cnt[base + 2] : 0;
        int v3 = (base + 3 < NBKT) ? cnt[base + 3] : 0;
        int s = v0 + v1 + v2 + v3;
        int lane = t & 63, w = t >> 6;
        int x = s;
#pragma unroll
        for (int o = 1; o < 64; o <<= 1) {
            int u = __shfl_up(x, o, 64);
            if (lane >= o) x += u;
        }
        if (lane == 63) wsum[w] = x;
        __syncthreads();
        int woff = 0;
        for (int k = 0; k < 4; k++) woff += (k < w) ? wsum[k] : 0;
        int run = woff + x - s;
        if (base + 0 < NBKT) { off[base + 0] = run; cur[base + 0] = run; } run += v0;
        if (base + 1 < NBKT) { off[base + 1] = run; cur[base + 1] = run; } run += v1;
        if (base + 2 < NBKT) { off[base + 2] = run; cur[base + 2] = run; } run += v2;
        if (base + 3 < NBKT) { off[base + 3] = run; cur[base + 3] = run; } run += v3;
    }
    __syncthreads();
    // phase c: permute into bucket-grouped order (src/dst re-read hits L2)
    for (int i = t; i < len; i += blockDim.x) {
        int d = dst[beg + i];
        int s = src[beg + i];
        int b = d >> 7;
        int pos = atomicAdd(&cur[b], 1);
        bufB[pos] = (unsigned)s | ((unsigned)(d & 127) << 17);
        binarr2[pos] = (unsigned short)b;
    }
    __syncthreads();
    // phase d: full-lane sorted-order write (runs are dest-contiguous)
    for (int i = t; i < len; i += blockDim.x) {
        int b = binarr2[i];
        packed[gbase[b] + i - off[b]] = bufB[i];
    }
}

// ---- fused: per-bucket count + scan + dis/y4/rowptr + in-place node sort
__global__ void k_sort(unsigned int* __restrict__ packed, const int* __restrict__ bbase,
                       const float* __restrict__ x, float* __restrict__ dis,
                       float4* __restrict__ y4, int* __restrict__ rowptr, int N, int E) {
    __shared__ unsigned int buf[BUFSZ];
    __shared__ int cnt[BKT];
    __shared__ int sc[BKT];
    __shared__ int cur[BKT];
    int b = blockIdx.x, t = threadIdx.x;
    int beg = bbase[b], end = bbase[b + 1];
    int len = end - beg;
    for (int i = t; i < len; i += blockDim.x) buf[i] = packed[beg + i];
    if (t < BKT) cnt[t] = 0;
    __syncthreads();
    for (int i = t; i < len; i += blockDim.x)
        atomicAdd(&cnt[buf[i] >> 17], 1);
    __syncthreads();
    int v = 0;
    if (t < BKT) { v = cnt[t]; sc[t] = v; }
    __syncthreads();
    for (int off = 1; off < BKT; off <<= 1) {
        int u = 0;
        if (t < BKT && t >= off) u = sc[t - off];
        __syncthreads();
        if (t < BKT) sc[t] += u;
        __syncthreads();
    }
    if (t < BKT) {
        int excl = sc[t] - v;
        cur[t] = excl;
        int gi = b * BKT + t;
        if (gi < N) {
            rowptr[gi] = beg + excl;
            float di = rsqrtf((float)v + 1.0f);      // + self loop
            dis[gi] = di;
            float4 y;
            y.x = di * x[3 * gi + 0];
            y.y = di * x[3 * gi + 1];
            y.z = di * x[3 * gi + 2];
            y.w = 0.0f;
            y4[gi] = y;
        }
    }
    __syncthreads();
    for (int i = t; i < len; i += blockDim.x) {
        unsigned vv = buf[i];
        int pos = atomicAdd(&cur[vv >> 17], 1);      // LDS atomic
        packed[beg + pos] = vv & 0x1FFFF;            // plain src id, node-sorted
    }
    if (b == 0 && t == 0) rowptr[N] = E;
}

// ---- layer 1: node-parallel, 32 lanes/node gather y4 (1.6MB, L2-resident)
// writes g as TWO half-tables: g0=[N][16] (f0..15), g1=[N][16] (f16..31)
__global__ void k_l1(const unsigned int* __restrict__ csr, const int* __restrict__ rowptr,
                     const float4* __restrict__ y4, const float* __restrict__ dis,
                     const float* __restrict__ W1, const float* __restrict__ b1,
                     __half* __restrict__ g, int N) {
    int t = blockIdx.x * blockDim.x + threadIdx.x;
    int i = t >> 5, j = t & 31;
    if (i >= N) return;
    int beg = rowptr[i], end = rowptr[i + 1];
    float ax = 0.f, ay = 0.f, az = 0.f;
    for (int e = beg + j; e < end; e += 32) {
        float4 yv = y4[csr[e]];
        ax += yv.x; ay += yv.y; az += yv.z;
    }
#pragma unroll
    for (int m = 16; m >= 1; m >>= 1) {
        ax += __shfl_xor(ax, m, 32);
        ay += __shfl_xor(ay, m, 32);
        az += __shfl_xor(az, m, 32);
    }
    float di = dis[i];
    float4 ys = y4[i];                               // self loop (pre-scaled)
    float a0 = di * (ax + ys.x);
    float a1 = di * (ay + ys.y);
    float a2 = di * (az + ys.z);
    float h = b1[j] + a0 * W1[j] + a1 * W1[32 + j] + a2 * W1[64 + j];
    __half* gb = g + (size_t)(j >> 4) * ((size_t)N * 16);   // half-table select
    gb[(size_t)i * 16 + (j & 15)] = __float2half(di * fmaxf(h, 0.f));
}

// unpack-accumulate one uint4 (8 halves) into 8 fp32 accumulators
__device__ __forceinline__ void acc8(float* a, uint4 r) {
    const __half2* h = (const __half2*)&r;
#pragma unroll
    for (int k = 0; k < 4; k++) {
        float2 f = __half22float2(h[k]);
        a[2 * k]     += f.x;
        a[2 * k + 1] += f.y;
    }
}

// unpack one uint4 (8 halves) into 8 floats
__device__ __forceinline__ void unp8(float* a, uint4 r) {
    const __half2* h = (const __half2*)&r;
#pragma unroll
    for (int k = 0; k < 4; k++) {
        float2 f = __half22float2(h[k]);
        a[2 * k]     = f.x;
        a[2 * k + 1] = f.y;
    }
}

// ---- layer 2 pass A: 4 lanes/node, each lane gathers whole 32B g0 rows
// (2x dwordx4) for its stride-4 edge slice; 16 fp32 reg accumulators;
// butterfly reduce; lane 0 packs fp16 partial into `part` (aliases hist).
__global__ void k_l2a(const unsigned int* __restrict__ csr, const int* __restrict__ rowptr,
                      const __half* __restrict__ g0, const float* __restrict__ dis,
                      __half* __restrict__ part, int N) {
    int t = blockIdx.x * blockDim.x + threadIdx.x;
    int i = t >> 2, l = t & 3;
    if (i >= N) return;
    int beg = rowptr[i], end = rowptr[i + 1];
    const uint4* gq = (const uint4*)g0;             // 2 uint4 per 16-feature row
    float acc[16];
#pragma unroll
    for (int f = 0; f < 16; f++) acc[f] = 0.f;
    int e = beg + l;
    for (; e + 4 < end; e += 8) {                   // 2-edge unroll: 4 loads in flight
        int s0 = csr[e], s1 = csr[e + 4];
        uint4 r0 = gq[2 * (size_t)s0], r1 = gq[2 * (size_t)s0 + 1];
        uint4 r2 = gq[2 * (size_t)s1], r3 = gq[2 * (size_t)s1 + 1];
        acc8(acc, r0); acc8(acc + 8, r1);
        acc8(acc, r2); acc8(acc + 8, r3);
    }
    if (e < end) {
        int s = csr[e];
        uint4 r0 = gq[2 * (size_t)s], r1 = gq[2 * (size_t)s + 1];
        acc8(acc, r0); acc8(acc + 8, r1);
    }
#pragma unroll
    for (int f = 0; f < 16; f++) {                  // 4-lane butterfly
        acc[f] += __shfl_xor(acc[f], 1, 4);
        acc[f] += __shfl_xor(acc[f], 2, 4);
    }
    if (l == 0) {
        float di = dis[i];
        float sf[16];
        unp8(sf, gq[2 * (size_t)i]);                // self-loop row
        unp8(sf + 8, gq[2 * (size_t)i + 1]);
        uint4 w0, w1;
        __half2* p0 = (__half2*)&w0;
        __half2* p1 = (__half2*)&w1;
#pragma unroll
        for (int k = 0; k < 4; k++) {
            p0[k] = __floats2half2_rn(di * (acc[2 * k] + sf[2 * k]),
                                      di * (acc[2 * k + 1] + sf[2 * k + 1]));
            p1[k] = __floats2half2_rn(di * (acc[8 + 2 * k] + sf[8 + 2 * k]),
                                      di * (acc[8 + 2 * k + 1] + sf[8 + 2 * k + 1]));
        }
        uint4* pq = (uint4*)part;
        pq[2 * (size_t)i]     = w0;
        pq[2 * (size_t)i + 1] = w1;
    }
}

// ---- layer 2 pass B: same gather structure over g1 (f16..31), reload part,
// full 32x32 W2 matmul per node: lane l computes outputs 8l..8l+7 via
// fully-unrolled register FMAs; relu; W3 dot; 4-lane reduce -> q.
__global__ void k_l2b(const unsigned int* __restrict__ csr, const int* __restrict__ rowptr,
                      const __half* __restrict__ g1, const float* __restrict__ dis,
                      const __half* __restrict__ part,
                      const float* __restrict__ W2, const float* __restrict__ b2,
                      const float* __restrict__ W3, float* __restrict__ q, int N) {
    int t = blockIdx.x * blockDim.x + threadIdx.x;
    int i = t >> 2, l = t & 3;
    if (i >= N) return;
    int beg = rowptr[i], end = rowptr[i + 1];
    const uint4* gq = (const uint4*)g1;
    float acc[16];
#pragma unroll
    for (int f = 0; f < 16; f++) acc[f] = 0.f;
    int e = beg + l;
    for (; e + 4 < end; e += 8) {
        int s0 = csr[e], s1 = csr[e + 4];
        uint4 r0 = gq[2 * (size_t)s0], r1 = gq[2 * (size_t)s0 + 1];
        uint4 r2 = gq[2 * (size_t)s1], r3 = gq[2 * (size_t)s1 + 1];
        acc8(acc, r0); acc8(acc + 8, r1);
        acc8(acc, r2); acc8(acc + 8, r3);
    }
    if (e < end) {
        int s = csr[e];
        uint4 r0 = gq[2 * (size_t)s], r1 = gq[2 * (size_t)s + 1];
        acc8(acc, r0); acc8(acc + 8, r1);
    }
#pragma unroll
    for (int f = 0; f < 16; f++) {
        acc[f] += __shfl_xor(acc[f], 1, 4);
        acc[f] += __shfl_xor(acc[f], 2, 4);
    }
    // assemble full 32-feature activation av[0..31] (all constant-indexed)
    float av[32];
    const uint4* pq = (const uint4*)part;
    unp8(av, pq[2 * (size_t)i]);                    // f0..15 (already di-scaled)
    unp8(av + 8, pq[2 * (size_t)i + 1]);
    float sf[16];
    unp8(sf, gq[2 * (size_t)i]);                    // self-loop row (hi half)
    unp8(sf + 8, gq[2 * (size_t)i + 1]);
    float di = dis[i];
#pragma unroll
    for (int f = 0; f < 16; f++) av[16 + f] = di * (acc[f] + sf[f]);
    // W2 matmul: lane l -> outputs m = 8l..8l+7
    float o[8];
    const float* bb = b2 + 8 * l;
#pragma unroll
    for (int m = 0; m < 8; m++) o[m] = bb[m];
    const float* wbase = W2 + 8 * l;
#pragma unroll
    for (int k = 0; k < 32; k++) {
        float a = av[k];
        const float* wr = wbase + k * 32;
#pragma unroll
        for (int m = 0; m < 8; m++) o[m] = fmaf(a, wr[m], o[m]);
    }
    const float* w3 = W3 + 8 * l;
    float c = 0.f;
#pragma unroll
    for (int m = 0; m < 8; m++) c += fmaxf(o[m], 0.f) * w3[m];
    c += __shfl_xor(c, 1, 4);
    c += __shfl_xor(c, 2, 4);
    if (l == 0) q[i] = di * c;                      // q = dis * p
}

// ---- layer 3: node-parallel scalar q gathers (q 400KB, L2-resident)
__global__ void k_l3(const unsigned int* __restrict__ csr, const int* __restrict__ rowptr,
                     const float* __restrict__ q, const float* __restrict__ dis,
                     const float* __restrict__ b3, float* __restrict__ out, int N) {
    int t = blockIdx.x * blockDim.x + threadIdx.x;
    int i = t >> 5, j = t & 31;
    if (i >= N) return;
    int beg = rowptr[i], end = rowptr[i + 1];
    float acc = 0.f;
    for (int e = beg + j; e < end; e += 32)
        acc += q[csr[e]];
#pragma unroll
    for (int m = 16; m >= 1; m >>= 1)
        acc += __shfl_xor(acc, m, 32);
    if (j == 0) out[i] = dis[i] * (acc + q[i]) + b3[0];
}

extern "C" void kernel_launch(void* const* d_in, const int* in_sizes, int n_in,
                              void* d_out, int out_size, void* d_ws, size_t ws_size,
                              hipStream_t stream) {
    const float* x  = (const float*)d_in[0];
    const int*   ei = (const int*)d_in[1];
    const float* W1 = (const float*)d_in[2];
    const float* b1 = (const float*)d_in[3];
    const float* W2 = (const float*)d_in[4];
    const float* b2 = (const float*)d_in[5];
    const float* W3 = (const float*)d_in[6];
    const float* b3 = (const float*)d_in[7];
    float* out = (float*)d_out;

    int N = in_sizes[0] / 3;
    int E = in_sizes[1] / 2;
    const int* src = ei;
    const int* dst = ei + E;

    // workspace (all init done in-kernel; no memset needed), 256B-aligned carves
    char* w = (char*)d_ws;
#define CARVE(nbytes) w; w += (((size_t)(nbytes) + 255) & ~(size_t)255)
    int*   hist   = (int*)  CARVE((size_t)SB * NBKT * 4);   // 4.0 MB
    int*   btot   = (int*)  CARVE((size_t)MAXNB * 4);
    int*   bbase  = (int*)  CARVE((size_t)(MAXNB + 1) * 4);
    int*   rowptr = (int*)  CARVE((size_t)(N + 1) * 4);
    float* dis    = (float*)CARVE((size_t)N * 4);
    float* y4     = (float*)CARVE((size_t)N * 16);
    __half* g     = (__half*)CARVE((size_t)N * 32 * 2);     // 6.4 MB fp16 (two halves)
    float* q      = (float*)CARVE((size_t)N * 4);
    unsigned int* packed = (unsigned int*)CARVE((size_t)E * 4);  // 25.6 MB
#undef CARVE

    // part[N][16] fp16 (3.2MB) aliases hist (4.0MB, dead after k_bsort)
    __half* part = (__half*)hist;
    __half* g0 = g;
    __half* g1 = g + (size_t)N * 16;

    k_hist <<<SB, BLK, 0, stream>>>(dst, hist, E);
    k_scanA<<<NBKT, BLK, 0, stream>>>(hist, btot, NBKT);
    k_scanB<<<1, MAXNB, 0, stream>>>(btot, bbase, NBKT, E);
    k_bsort<<<SB, BLK, 0, stream>>>(src, dst, hist, bbase, packed, E);
    k_sort <<<NBKT, BLK, 0, stream>>>(packed, bbase, x, dis, (float4*)y4, rowptr, N, E);

    long long tn = (long long)N * 32;
    unsigned gn = (unsigned)((tn + BLK - 1) / BLK);
    long long tn4 = (long long)N * 4;
    unsigned gn4 = (unsigned)((tn4 + BLK - 1) / BLK);
    k_l1 <<<gn,  BLK, 0, stream>>>(packed, rowptr, (const float4*)y4, dis, W1, b1, g, N);
    k_l2a<<<gn4, BLK, 0, stream>>>(packed, rowptr, g0, dis, part, N);
    k_l2b<<<gn4, BLK, 0, stream>>>(packed, rowptr, g1, dis, part, W2, b2, W3, q, N);
    k_l3 <<<gn,  BLK, 0, stream>>>(packed, rowptr, q, dis, b3, out, N);
}

// Round 3
// 348.836 us; speedup vs baseline: 1.1567x; 1.1567x over previous
//
#include <hip/hip_runtime.h>
#include <hip/hip_fp16.h>

// GCN 3->32->32->1, N=100K, E=6.4M (+self loops).
// R9 lesson: L2-resident gathers alone don't help (46% VALU at 35MB FETCH)
//   -> k_l2 is ISSUE-bound; feature-split doubled shfl/csr work -> slower.
// R10 lesson: 4-lane/node full-row gathers cut VALU to 15% but killed TLP
//   (400K threads) and de-coalesced gathers (64 rows/instr) -> latency-bound.
// R11: 8 lanes/node, lane j owns features 4j..4j+3. Per edge: 1 broadcast
//   csr load + one 8B dwordx2 gather (8 lanes = full 64B row, coalesced)
//   + 4 cvt/add  ->  ~96 lane-ops/edge vs R8's ~190, NO reduce butterfly.
//   TLP 800K threads, 8-edge unroll (8 gathers in flight). Epilogue: 32
//   shfl + 128 FMA per lane (same total as R8).
//   k_sort bins by (d&127)*4 | (src>>15): rows' edges grouped in 4
//   src-quarters -> phase-coherent ~2MB gather window (per-XCD L2).
// Carried from R8: fp16 g single table, fused k_sort, node-parallel
//   k_l1/k_l3, zero global atomics, 256B-aligned carves.

#define BLK 256
#define SB 1280          // chunks; SB*CHUNK == E exactly
#define CHUNK 5000
#define BKT 128          // nodes per bucket
#define NBKT 782         // ceil(100000/128)
#define MAXNB 1024       // scanB width >= NBKT
#define BUFSZ 15360      // k_sort bucket buffer (mean 8192, ~79 sigma)

// ---- pass 1: per-chunk histogram over dst buckets (LDS, int4 loads)
__global__ void k_hist(const int* __restrict__ dst, int* __restrict__ hist, int E) {
    __shared__ int lh[NBKT];
    for (int b = threadIdx.x; b < NBKT; b += blockDim.x) lh[b] = 0;
    __syncthreads();
    int beg = blockIdx.x * CHUNK;
    int end = min(E, beg + CHUNK);
    int nq = (end - beg) >> 2;                    // full int4 quads
    const int4* d4 = (const int4*)(dst + beg);
    for (int i = threadIdx.x; i < nq; i += blockDim.x) {
        int4 d = d4[i];
        atomicAdd(&lh[d.x >> 7], 1);
        atomicAdd(&lh[d.y >> 7], 1);
        atomicAdd(&lh[d.z >> 7], 1);
        atomicAdd(&lh[d.w >> 7], 1);
    }
    for (int e = beg + (nq << 2) + threadIdx.x; e < end; e += blockDim.x)
        atomicAdd(&lh[dst[e] >> 7], 1);
    __syncthreads();
    for (int b = threadIdx.x; b < NBKT; b += blockDim.x)
        hist[(size_t)blockIdx.x * NBKT + b] = lh[b];
}

// ---- scan A: per bucket, exclusive-scan its SB chunk-counts (shfl, 5 items/thr)
__global__ void k_scanA(int* __restrict__ hist, int* __restrict__ btot, int NB) {
    int b = blockIdx.x, t = threadIdx.x;          // 256 threads * 5 items = 1280
    int base = t * 5;
    int v0 = hist[(size_t)(base + 0) * NB + b];
    int v1 = hist[(size_t)(base + 1) * NB + b];
    int v2 = hist[(size_t)(base + 2) * NB + b];
    int v3 = hist[(size_t)(base + 3) * NB + b];
    int v4 = hist[(size_t)(base + 4) * NB + b];
    int s = v0 + v1 + v2 + v3 + v4;
    int lane = t & 63, w = t >> 6;
    int x = s;
#pragma unroll
    for (int off = 1; off < 64; off <<= 1) {
        int u = __shfl_up(x, off, 64);
        if (lane >= off) x += u;
    }
    __shared__ int wsum[4];
    if (lane == 63) wsum[w] = x;
    __syncthreads();
    int woff = 0;
    for (int k = 0; k < 4; k++) woff += (k < w) ? wsum[k] : 0;
    int run = woff + x - s;                       // exclusive prefix for item 0
    hist[(size_t)(base + 0) * NB + b] = run;  run += v0;
    hist[(size_t)(base + 1) * NB + b] = run;  run += v1;
    hist[(size_t)(base + 2) * NB + b] = run;  run += v2;
    hist[(size_t)(base + 3) * NB + b] = run;  run += v3;
    hist[(size_t)(base + 4) * NB + b] = run;  run += v4;
    if (t == 255) btot[b] = run;
}

// ---- scan B: exclusive-scan bucket totals -> bucket base offsets
__global__ void k_scanB(const int* __restrict__ btot, int* __restrict__ bbase,
                        int NB, int E) {
    __shared__ int sh[MAXNB];
    int t = threadIdx.x;
    int v = (t < NB) ? btot[t] : 0;
    sh[t] = v;
    __syncthreads();
    for (int off = 1; off < MAXNB; off <<= 1) {
        int u = (t >= off) ? sh[t - off] : 0;
        __syncthreads();
        sh[t] += u;
        __syncthreads();
    }
    if (t < NB) bbase[t] = sh[t] - v;
    if (t == 0) bbase[NB] = E;
}

// ---- pass 2: LDS chunk-sort by bucket, full-lane sorted-order streaming
__global__ void k_bsort(const int* __restrict__ src, const int* __restrict__ dst,
                        const int* __restrict__ hist, const int* __restrict__ bbase,
                        unsigned int* __restrict__ packed, int E) {
    __shared__ unsigned int bufB[CHUNK];          // 20 KB
    __shared__ unsigned short binarr2[CHUNK];     // 10 KB (bucket of sorted pos)
    __shared__ int cnt[NBKT];
    __shared__ int off[NBKT];
    __shared__ int cur[NBKT];
    __shared__ int gbase[NBKT];
    __shared__ int wsum[4];
    int t = threadIdx.x;
    int beg = blockIdx.x * CHUNK;
    int end = min(E, beg + CHUNK);
    int len = end - beg;
    for (int b = t; b < NBKT; b += blockDim.x) {
        cnt[b] = 0;
        gbase[b] = bbase[b] + hist[(size_t)blockIdx.x * NBKT + b];
    }
    __syncthreads();
    // phase a: count (int4 loads)
    {
        int nq = len >> 2;
        const int4* d4 = (const int4*)(dst + beg);
        for (int i = t; i < nq; i += blockDim.x) {
            int4 d = d4[i];
            atomicAdd(&cnt[d.x >> 7], 1);
            atomicAdd(&cnt[d.y >> 7], 1);
            atomicAdd(&cnt[d.z >> 7], 1);
            atomicAdd(&cnt[d.w >> 7], 1);
        }
        for (int i = (nq << 2) + t; i < len; i += blockDim.x)
            atomicAdd(&cnt[dst[beg + i] >> 7], 1);
    }
    __syncthreads();
    // phase b: exclusive scan of 782 counts (4 items/thread, shfl)
    {
        int base = t * 4;
        int v0 = (base + 0 < NBKT) ? cnt[base + 0] : 0;
        int v1 = (base + 1 < NBKT) ? cnt[base + 1] : 0;
        int v2 = (base + 2 < NBKT) ? cnt[base + 2] : 0;
        int v3 = (base + 3 < NBKT) ? cnt[base + 3] : 0;
        int s = v0 + v1 + v2 + v3;
        int lane = t & 63, w = t >> 6;
        int x = s;
#pragma unroll
        for (int o = 1; o < 64; o <<= 1) {
            int u = __shfl_up(x, o, 64);
            if (lane >= o) x += u;
        }
        if (lane == 63) wsum[w] = x;
        __syncthreads();
        int woff = 0;
        for (int k = 0; k < 4; k++) woff += (k < w) ? wsum[k] : 0;
        int run = woff + x - s;
        if (base + 0 < NBKT) { off[base + 0] = run; cur[base + 0] = run; } run += v0;
        if (base + 1 < NBKT) { off[base + 1] = run; cur[base + 1] = run; } run += v1;
        if (base + 2 < NBKT) { off[base + 2] = run; cur[base + 2] = run; } run += v2;
        if (base + 3 < NBKT) { off[base + 3] = run; cur[base + 3] = run; } run += v3;
    }
    __syncthreads();
    // phase c: permute into bucket-grouped order (src/dst re-read hits L2)
    for (int i = t; i < len; i += blockDim.x) {
        int d = dst[beg + i];
        int s = src[beg + i];
        int b = d >> 7;
        int pos = atomicAdd(&cur[b], 1);
        bufB[pos] = (unsigned)s | ((unsigned)(d & 127) << 17);
        binarr2[pos] = (unsigned short)b;
    }
    __syncthreads();
    // phase d: full-lane sorted-order write (runs are dest-contiguous)
    for (int i = t; i < len; i += blockDim.x) {
        int b = binarr2[i];
        packed[gbase[b] + i - off[b]] = bufB[i];
    }
}

// ---- fused: per-bucket 512-bin count (node x src-quarter) + scan +
// dis/y4/rowptr + in-place sort: node-major, src-quarter-minor order.
__global__ void k_sort(unsigned int* __restrict__ packed, const int* __restrict__ bbase,
                       const float* __restrict__ x, float* __restrict__ dis,
                       float4* __restrict__ y4, int* __restrict__ rowptr, int N, int E) {
    __shared__ unsigned int buf[BUFSZ];
    __shared__ int cnt[4 * BKT];                  // 512 bins
    __shared__ int cur[4 * BKT];
    __shared__ int wsum[4];
    int b = blockIdx.x, t = threadIdx.x;
    int beg = bbase[b], end = bbase[b + 1];
    int len = end - beg;
    for (int i = t; i < len; i += blockDim.x) buf[i] = packed[beg + i];
    cnt[t] = 0; cnt[t + 256] = 0;
    __syncthreads();
    for (int i = t; i < len; i += blockDim.x) {
        unsigned v = buf[i];
        int key = (int)((v >> 17) << 2) | (int)((v & 0x1FFFFu) >> 15);
        atomicAdd(&cnt[key], 1);
    }
    __syncthreads();
    // exclusive scan over 512 bins, 2 items/thread (shfl + wave sums)
    {
        int v0 = cnt[2 * t], v1 = cnt[2 * t + 1];
        int s = v0 + v1;
        int lane = t & 63, w = t >> 6;
        int xs = s;
#pragma unroll
        for (int o = 1; o < 64; o <<= 1) {
            int u = __shfl_up(xs, o, 64);
            if (lane >= o) xs += u;
        }
        if (lane == 63) wsum[w] = xs;
        __syncthreads();
        int woff = 0;
        for (int k = 0; k < 4; k++) woff += (k < w) ? wsum[k] : 0;
        int run = woff + xs - s;
        cur[2 * t] = run;
        cur[2 * t + 1] = run + v0;
    }
    __syncthreads();
    if (t < BKT) {
        int excl = cur[4 * t];                    // node segment start
        int v = cnt[4 * t] + cnt[4 * t + 1] + cnt[4 * t + 2] + cnt[4 * t + 3];
        int gi = b * BKT + t;
        if (gi < N) {
            rowptr[gi] = beg + excl;
            float di = rsqrtf((float)v + 1.0f);   // + self loop
            dis[gi] = di;
            float4 y;
            y.x = di * x[3 * gi + 0];
            y.y = di * x[3 * gi + 1];
            y.z = di * x[3 * gi + 2];
            y.w = 0.0f;
            y4[gi] = y;
        }
    }
    __syncthreads();
    for (int i = t; i < len; i += blockDim.x) {
        unsigned vv = buf[i];
        int key = (int)((vv >> 17) << 2) | (int)((vv & 0x1FFFFu) >> 15);
        int pos = atomicAdd(&cur[key], 1);        // LDS atomic
        packed[beg + pos] = vv & 0x1FFFF;         // plain src id
    }
    if (b == 0 && t == 0) rowptr[N] = E;
}

// ---- layer 1: node-parallel, 32 lanes/node gather y4 (1.6MB, L2-resident)
__global__ void k_l1(const unsigned int* __restrict__ csr, const int* __restrict__ rowptr,
                     const float4* __restrict__ y4, const float* __restrict__ dis,
                     const float* __restrict__ W1, const float* __restrict__ b1,
                     __half* __restrict__ g, int N) {
    int t = blockIdx.x * blockDim.x + threadIdx.x;
    int i = t >> 5, j = t & 31;
    if (i >= N) return;
    int beg = rowptr[i], end = rowptr[i + 1];
    float ax = 0.f, ay = 0.f, az = 0.f;
    for (int e = beg + j; e < end; e += 32) {
        float4 yv = y4[csr[e]];
        ax += yv.x; ay += yv.y; az += yv.z;
    }
#pragma unroll
    for (int m = 16; m >= 1; m >>= 1) {
        ax += __shfl_xor(ax, m, 32);
        ay += __shfl_xor(ay, m, 32);
        az += __shfl_xor(az, m, 32);
    }
    float di = dis[i];
    float4 ys = y4[i];                               // self loop (pre-scaled)
    float a0 = di * (ax + ys.x);
    float a1 = di * (ay + ys.y);
    float a2 = di * (az + ys.z);
    float h = b1[j] + a0 * W1[j] + a1 * W1[32 + j] + a2 * W1[64 + j];
    g[(size_t)i * 32 + j] = __float2half(di * fmaxf(h, 0.f));
}

// unpack one uint2 (4 halves) and accumulate into 4 fp32 accumulators
__device__ __forceinline__ void acc4(float& c0, float& c1, float& c2, float& c3,
                                     uint2 r) {
    __half2 a = *(const __half2*)&r.x;
    __half2 b = *(const __half2*)&r.y;
    float2 fa = __half22float2(a);
    float2 fb = __half22float2(b);
    c0 += fa.x; c1 += fa.y; c2 += fb.x; c3 += fb.y;
}

// ---- layer 2 (+L3 projection): 8 lanes/node, lane j owns features 4j..4j+3.
// Per edge: broadcast csr load + one 8B dwordx2 gather (8 lanes = full 64B
// row, line-coalesced) + 4 cvt/add. No reduce butterfly. 8-edge unroll.
__global__ void k_l2(const unsigned int* __restrict__ csr, const int* __restrict__ rowptr,
                     const __half* __restrict__ g, const float* __restrict__ dis,
                     const float* __restrict__ W2, const float* __restrict__ b2,
                     const float* __restrict__ W3, float* __restrict__ q, int N) {
    int t = blockIdx.x * blockDim.x + threadIdx.x;
    int i = t >> 3, j = t & 7;
    if (i >= N) return;
    int beg = rowptr[i], end = rowptr[i + 1];
    const uint2* g2 = (const uint2*)g;               // [N][8] x 8B slices
    float c0 = 0.f, c1 = 0.f, c2 = 0.f, c3 = 0.f;
    int e = beg;
    for (; e + 8 <= end; e += 8) {
        int s0 = (int)csr[e + 0], s1 = (int)csr[e + 1];
        int s2 = (int)csr[e + 2], s3 = (int)csr[e + 3];
        int s4 = (int)csr[e + 4], s5 = (int)csr[e + 5];
        int s6 = (int)csr[e + 6], s7 = (int)csr[e + 7];
        uint2 r0 = g2[s0 * 8 + j];
        uint2 r1 = g2[s1 * 8 + j];
        uint2 r2 = g2[s2 * 8 + j];
        uint2 r3 = g2[s3 * 8 + j];
        uint2 r4 = g2[s4 * 8 + j];
        uint2 r5 = g2[s5 * 8 + j];
        uint2 r6 = g2[s6 * 8 + j];
        uint2 r7 = g2[s7 * 8 + j];
        acc4(c0, c1, c2, c3, r0);
        acc4(c0, c1, c2, c3, r1);
        acc4(c0, c1, c2, c3, r2);
        acc4(c0, c1, c2, c3, r3);
        acc4(c0, c1, c2, c3, r4);
        acc4(c0, c1, c2, c3, r5);
        acc4(c0, c1, c2, c3, r6);
        acc4(c0, c1, c2, c3, r7);
    }
    for (; e < end; e++) {
        int s = (int)csr[e];
        uint2 r = g2[s * 8 + j];
        acc4(c0, c1, c2, c3, r);
    }
    float di = dis[i];
    uint2 rs = g2[i * 8 + j];                        // self-loop slice
    float2 sa = __half22float2(*(const __half2*)&rs.x);
    float2 sb = __half22float2(*(const __half2*)&rs.y);
    float a0 = di * (c0 + sa.x);
    float a1 = di * (c1 + sa.y);
    float a2 = di * (c2 + sb.x);
    float a3 = di * (c3 + sb.y);
    // W2 matmul: lane j -> outputs m=4j..4j+3 (W2 is [32 in][32 out] row-major)
    int m = 4 * j;
    float o0 = b2[m + 0], o1 = b2[m + 1], o2 = b2[m + 2], o3 = b2[m + 3];
#pragma unroll
    for (int kl = 0; kl < 8; kl++) {
        float x0 = __shfl(a0, kl, 8);                // a[4kl+0]
        float x1 = __shfl(a1, kl, 8);
        float x2 = __shfl(a2, kl, 8);
        float x3 = __shfl(a3, kl, 8);
        const float* w0 = W2 + (4 * kl) * 32 + m;    // rows 4kl..4kl+3, cols m..m+3
        o0 = fmaf(x0, w0[0], fmaf(x1, w0[32], fmaf(x2, w0[64], fmaf(x3, w0[96], o0))));
        o1 = fmaf(x0, w0[1], fmaf(x1, w0[33], fmaf(x2, w0[65], fmaf(x3, w0[97], o1))));
        o2 = fmaf(x0, w0[2], fmaf(x1, w0[34], fmaf(x2, w0[66], fmaf(x3, w0[98], o2))));
        o3 = fmaf(x0, w0[3], fmaf(x1, w0[35], fmaf(x2, w0[67], fmaf(x3, w0[99], o3))));
    }
    float cc = fmaxf(o0, 0.f) * W3[m + 0] + fmaxf(o1, 0.f) * W3[m + 1]
             + fmaxf(o2, 0.f) * W3[m + 2] + fmaxf(o3, 0.f) * W3[m + 3];
    cc += __shfl_xor(cc, 1, 8);
    cc += __shfl_xor(cc, 2, 8);
    cc += __shfl_xor(cc, 4, 8);
    if (j == 0) q[i] = di * cc;                      // q = dis * p
}

// ---- layer 3: node-parallel scalar q gathers (q 400KB, L2-resident)
__global__ void k_l3(const unsigned int* __restrict__ csr, const int* __restrict__ rowptr,
                     const float* __restrict__ q, const float* __restrict__ dis,
                     const float* __restrict__ b3, float* __restrict__ out, int N) {
    int t = blockIdx.x * blockDim.x + threadIdx.x;
    int i = t >> 5, j = t & 31;
    if (i >= N) return;
    int beg = rowptr[i], end = rowptr[i + 1];
    float acc = 0.f;
    for (int e = beg + j; e < end; e += 32)
        acc += q[csr[e]];
#pragma unroll
    for (int m = 16; m >= 1; m >>= 1)
        acc += __shfl_xor(acc, m, 32);
    if (j == 0) out[i] = dis[i] * (acc + q[i]) + b3[0];
}

extern "C" void kernel_launch(void* const* d_in, const int* in_sizes, int n_in,
                              void* d_out, int out_size, void* d_ws, size_t ws_size,
                              hipStream_t stream) {
    const float* x  = (const float*)d_in[0];
    const int*   ei = (const int*)d_in[1];
    const float* W1 = (const float*)d_in[2];
    const float* b1 = (const float*)d_in[3];
    const float* W2 = (const float*)d_in[4];
    const float* b2 = (const float*)d_in[5];
    const float* W3 = (const float*)d_in[6];
    const float* b3 = (const float*)d_in[7];
    float* out = (float*)d_out;

    int N = in_sizes[0] / 3;
    int E = in_sizes[1] / 2;
    const int* src = ei;
    const int* dst = ei + E;

    // workspace (all init done in-kernel; no memset needed), 256B-aligned carves
    char* w = (char*)d_ws;
#define CARVE(nbytes) w; w += (((size_t)(nbytes) + 255) & ~(size_t)255)
    int*   hist   = (int*)  CARVE((size_t)SB * NBKT * 4);   // 4.0 MB
    int*   btot   = (int*)  CARVE((size_t)MAXNB * 4);
    int*   bbase  = (int*)  CARVE((size_t)(MAXNB + 1) * 4);
    int*   rowptr = (int*)  CARVE((size_t)(N + 1) * 4);
    float* dis    = (float*)CARVE((size_t)N * 4);
    float* y4     = (float*)CARVE((size_t)N * 16);
    __half* g     = (__half*)CARVE((size_t)N * 32 * 2);     // 6.4 MB fp16
    float* q      = (float*)CARVE((size_t)N * 4);
    unsigned int* packed = (unsigned int*)CARVE((size_t)E * 4);  // 25.6 MB
#undef CARVE

    k_hist <<<SB, BLK, 0, stream>>>(dst, hist, E);
    k_scanA<<<NBKT, BLK, 0, stream>>>(hist, btot, NBKT);
    k_scanB<<<1, MAXNB, 0, stream>>>(btot, bbase, NBKT, E);
    k_bsort<<<SB, BLK, 0, stream>>>(src, dst, hist, bbase, packed, E);
    k_sort <<<NBKT, BLK, 0, stream>>>(packed, bbase, x, dis, (float4*)y4, rowptr, N, E);

    long long tn = (long long)N * 32;
    unsigned gn = (unsigned)((tn + BLK - 1) / BLK);
    long long tn8 = (long long)N * 8;
    unsigned gn8 = (unsigned)((tn8 + BLK - 1) / BLK);
    k_l1<<<gn,  BLK, 0, stream>>>(packed, rowptr, (const float4*)y4, dis, W1, b1, g, N);
    k_l2<<<gn8, BLK, 0, stream>>>(packed, rowptr, g, dis, W2, b2, W3, q, N);
    k_l3<<<gn,  BLK, 0, stream>>>(packed, rowptr, q, dis, b3, out, N);
}